// Round 13
// baseline (53.498 us; speedup 1.0000x reference)
//
#include <hip/hip_runtime.h>

// Conv2D 3x3 pad=1: x (32,64,64,64) f32 NCHW, w (128,64,3,3) OIHW, bias(128), out (32,128,64,64) f32.
// Barrier-free implicit GEMM (r6 structure, occupancy-fixed):
//   prep_xp: NCHW f32 -> padded+granule-swizzled xP[n][66][66][64ci] bf16 (slot = g^(wp&7))
//   prep_wA: OIHW f32 -> wA fragment-ordered bf16 (one Af = one coalesced 1KB dwordx4/wave)
//   conv_mfma13: grid (64,32) = 2048 blocks, 256 thr = 4 waves (2 cb x 2 sh).
//     Wave tile 64co x 32sp, acc 2x4 = 32 AGPR, ~72 combined regs -> 4 waves/SIMD.
//     LDS = 3-row X window only (25.3KB, gload_lds from xP) -> 4 blocks/CU = 16 indep waves.
//     ONE barrier total; K-loop: 4 global Af + 2 ds_read_b128 Bf + 8 MFMA per (p,c), no syncs.

typedef short short8 __attribute__((ext_vector_type(8)));
typedef float f32x4  __attribute__((ext_vector_type(4)));

static __device__ __forceinline__ unsigned short f2bf(float f) {
    unsigned int u = __float_as_uint(f);
    u = (u + 0x7FFFu + ((u >> 16) & 1u)) >> 16;   // RNE
    return (unsigned short)u;
}
static __device__ __forceinline__ unsigned int pk2(float lo, float hi) {
    return (unsigned int)f2bf(lo) | ((unsigned int)f2bf(hi) << 16);
}
static __device__ __forceinline__ void gload16(const void* g, void* l) {
    __builtin_amdgcn_global_load_lds(
        (const __attribute__((address_space(1))) void*)g,
        (__attribute__((address_space(3))) void*)l, 16, 0, 0);
}

// ---- prep_xp: x[n][ci][h][w] f32 -> xP[n][h'][w'][ci] bf16, padded (66x66), slot = g^(wp&7) ----
__global__ __launch_bounds__(256)
void prep_xp(const float* __restrict__ x, unsigned short* __restrict__ xP)
{
    const int hp = blockIdx.x, n = blockIdx.y, tid = threadIdx.x;
    unsigned short* rowBase = xP + (((size_t)n * 66 + hp) * 66) * 64;
    if (hp == 0 || hp == 65) {                    // zero border row
        uint4 z; z.x = z.y = z.z = z.w = 0u;
        for (int i = tid; i < 528; i += 256) ((uint4*)rowBase)[i] = z;
        return;
    }
    __shared__ float T[64][65];
    const int h = hp - 1;
    const size_t nbase = (size_t)n * 262144 + (size_t)h * 64;
    #pragma unroll
    for (int i = 0; i < 16; ++i) {
        int idx = tid + i * 256;                  // ci*64 + w
        int ci = idx >> 6, w = idx & 63;
        T[ci][w] = x[nbase + (size_t)ci * 4096 + w];
    }
    __syncthreads();
    if (tid < 16) {                               // zero border cols w'=0 and w'=65
        uint4 z; z.x = z.y = z.z = z.w = 0u;
        int wp = (tid >> 3) * 65;
        ((uint4*)(rowBase + wp * 64))[tid & 7] = z;
    }
    const int w = tid >> 2, cg = tid & 3;
    const int wp = w + 1;
    #pragma unroll
    for (int t = 0; t < 2; ++t) {
        const int g = cg * 2 + t;
        uint4 v;
        v.x = pk2(T[g*8+0][w], T[g*8+1][w]);
        v.y = pk2(T[g*8+2][w], T[g*8+3][w]);
        v.z = pk2(T[g*8+4][w], T[g*8+5][w]);
        v.w = pk2(T[g*8+6][w], T[g*8+7][w]);
        *(uint4*)(rowBase + wp * 64 + ((g ^ (wp & 7)) * 8)) = v;
    }
}

// ------- prep_wA: w[co][ci][3][3] f32 -> wA fragment order -------
// wA flat t = ((((cb*9 + p)*2 + c)*4 + mf)*64 + lane)*8 + j
//   co = cb*64 + mf*16 + (lane&15),  ci = c*32 + (lane>>4)*8 + j
__global__ __launch_bounds__(256)
void prep_wA(const float* __restrict__ w, unsigned short* __restrict__ wA)
{
    int t = blockIdx.x * 256 + threadIdx.x;
    if (t >= 73728) return;
    int j    = t & 7;
    int lane = (t >> 3) & 63;
    int mf   = (t >> 9) & 3;
    int c    = (t >> 11) & 1;
    int rest = t >> 12;            // 0..17
    int p    = rest % 9;
    int cb   = rest / 9;
    int co = cb * 64 + mf * 16 + (lane & 15);
    int ci = c * 32 + (lane >> 4) * 8 + j;
    wA[t] = f2bf(w[(size_t)(co * 64 + ci) * 9 + p]);
}

// ---------------- barrier-free MFMA conv ----------------
__global__ __launch_bounds__(256, 4)
void conv_mfma13(const unsigned short* __restrict__ xP,
                 const unsigned short* __restrict__ wA,
                 const float* __restrict__ bias,
                 float* __restrict__ out)
{
    __shared__ __align__(16) char lds[25344];     // 3 rows * 66 wp * 64 ci * 2B

    const int tid  = threadIdx.x;
    const int h    = blockIdx.x;        // 0..63 output row
    const int n    = blockIdx.y;        // 0..31
    const int wid  = tid >> 6, lane = tid & 63;
    const int cb   = wid >> 1;          // co half
    const int sh   = wid & 1;           // sp half (w 0..31 / 32..63)
    const int l15  = lane & 15, l4 = lane >> 4;

    const unsigned short* xPn = xP + (size_t)n * (66 * 66 * 64);
    const unsigned short* wAb = wA + (size_t)cb * 36864;

    // ---- prologue: stage 3 padded rows h..h+2 (pre-swizzled src, linear dest) ----
    #pragma unroll
    for (int k = 0; k < 7; ++k) {
        int G = tid + k * 256;          // 1584 granules = 3 * 528
        if (k < 6 || tid < 48) {
            int r = G / 528, gr = G - r * 528;
            gload16(xPn + ((size_t)(h + r) * 528 + gr) * 8, lds + r * 8448 + gr * 16);
        }
    }
    __syncthreads();                    // the ONLY barrier

    f32x4 acc[2][4];                    // acc[nf up to 2][mf 4]? -> [mf? no: [4mf][2nf] flattened below
    // acc[mf][nf]: mf 0..3 (co 16-blocks), nf 0..1 (sp 16-blocks)
    f32x4 a00=(f32x4)0.f,a01=(f32x4)0.f,a10=(f32x4)0.f,a11=(f32x4)0.f;
    f32x4 a20=(f32x4)0.f,a21=(f32x4)0.f,a30=(f32x4)0.f,a31=(f32x4)0.f;
    (void)acc;

    #pragma unroll
    for (int p = 0; p < 9; ++p) {
        const int kh = p / 3, kw = p - kh * 3;
        const char* xrow = lds + kh * 8448;
        #pragma unroll
        for (int c = 0; c < 2; ++c) {
            short8 Bf[2];
            #pragma unroll
            for (int nf = 0; nf < 2; ++nf) {
                const int wp = sh * 32 + nf * 16 + l15 + kw;
                Bf[nf] = *(const short8*)(xrow + wp * 128 + (((c * 4 + l4) ^ (wp & 7)) * 16));
            }
            short8 Af0 = *(const short8*)(wAb + ((((p * 2 + c) * 4 + 0) * 64 + lane) << 3));
            short8 Af1 = *(const short8*)(wAb + ((((p * 2 + c) * 4 + 1) * 64 + lane) << 3));
            short8 Af2 = *(const short8*)(wAb + ((((p * 2 + c) * 4 + 2) * 64 + lane) << 3));
            short8 Af3 = *(const short8*)(wAb + ((((p * 2 + c) * 4 + 3) * 64 + lane) << 3));
            __builtin_amdgcn_s_setprio(1);
            a00 = __builtin_amdgcn_mfma_f32_16x16x32_bf16(Af0, Bf[0], a00, 0, 0, 0);
            a01 = __builtin_amdgcn_mfma_f32_16x16x32_bf16(Af0, Bf[1], a01, 0, 0, 0);
            a10 = __builtin_amdgcn_mfma_f32_16x16x32_bf16(Af1, Bf[0], a10, 0, 0, 0);
            a11 = __builtin_amdgcn_mfma_f32_16x16x32_bf16(Af1, Bf[1], a11, 0, 0, 0);
            a20 = __builtin_amdgcn_mfma_f32_16x16x32_bf16(Af2, Bf[0], a20, 0, 0, 0);
            a21 = __builtin_amdgcn_mfma_f32_16x16x32_bf16(Af2, Bf[1], a21, 0, 0, 0);
            a30 = __builtin_amdgcn_mfma_f32_16x16x32_bf16(Af3, Bf[0], a30, 0, 0, 0);
            a31 = __builtin_amdgcn_mfma_f32_16x16x32_bf16(Af3, Bf[1], a31, 0, 0, 0);
            __builtin_amdgcn_s_setprio(0);
        }
    }

    // ---- epilogue: bias + store (C/D: col=lane&15, row=(lane>>4)*4+reg) ----
    {
        f32x4 am[4][2] = {{a00,a01},{a10,a11},{a20,a21},{a30,a31}};
        #pragma unroll
        for (int mf = 0; mf < 4; ++mf) {
            const f32x4 bv4 = *(const f32x4*)(bias + cb * 64 + mf * 16 + l4 * 4);
            #pragma unroll
            for (int r = 0; r < 4; ++r) {
                const int co = cb * 64 + mf * 16 + l4 * 4 + r;
                float* orow = out + (((size_t)n * 128 + co) * 64 + h) * 64;
                #pragma unroll
                for (int nf = 0; nf < 2; ++nf)
                    orow[sh * 32 + nf * 16 + l15] = am[mf][nf][r] + bv4[r];
            }
        }
    }
}

// ---------------- fp32 fallback if ws too small ----------------
__global__ __launch_bounds__(256, 4)
void conv2d_f32_tiled(const float* __restrict__ x,
                      const float* __restrict__ wgt,
                      const float* __restrict__ bias,
                      float* __restrict__ out)
{
    __shared__ float Xlds[8][10][66];
    __shared__ float Wlds[32][72];
    const int tid = threadIdx.x;
    const int co0 = blockIdx.x * 32, h0 = blockIdx.y * 8, n = blockIdx.z;
    const int tco = tid >> 6, lane = tid & 63;
    float acc[8][8];
    #pragma unroll
    for (int i = 0; i < 8; ++i)
        #pragma unroll
        for (int j = 0; j < 8; ++j) acc[i][j] = 0.0f;
    for (int cc = 0; cc < 8; ++cc) {
        const int ci0 = cc * 8;
        for (int idx = tid; idx < 8 * 10 * 66; idx += 256) {
            const int ww = idx % 66, t = idx / 66, hh = t % 10, ci = t / 10;
            const int gh = h0 + hh - 1, gw = ww - 1;
            float v = 0.0f;
            if ((unsigned)gh < 64u && (unsigned)gw < 64u)
                v = x[(((size_t)n * 64 + ci0 + ci) * 64 + gh) * 64 + gw];
            Xlds[ci][hh][ww] = v;
        }
        for (int idx = tid; idx < 32 * 72; idx += 256) {
            const int r = idx % 72, co = idx / 72;
            Wlds[co][r] = wgt[(size_t)(co0 + co) * 576 + ci0 * 9 + r];
        }
        __syncthreads();
        for (int ci = 0; ci < 8; ++ci)
            #pragma unroll
            for (int kh = 0; kh < 3; ++kh)
                #pragma unroll
                for (int kw = 0; kw < 3; ++kw) {
                    float wv[8];
                    #pragma unroll
                    for (int i = 0; i < 8; ++i) wv[i] = Wlds[tco * 8 + i][ci * 9 + kh * 3 + kw];
                    #pragma unroll
                    for (int j = 0; j < 8; ++j) {
                        const float xv = Xlds[ci][j + kh][lane + kw];
                        #pragma unroll
                        for (int i = 0; i < 8; ++i) acc[i][j] = fmaf(wv[i], xv, acc[i][j]);
                    }
                }
        __syncthreads();
    }
    #pragma unroll
    for (int i = 0; i < 8; ++i) {
        const int co = co0 + tco * 8 + i;
        const float b = bias[co];
        #pragma unroll
        for (int j = 0; j < 8; ++j)
            out[(((size_t)n * 128 + co) * 64 + (h0 + j)) * 64 + lane] = acc[i][j] + b;
    }
}

extern "C" void kernel_launch(void* const* d_in, const int* in_sizes, int n_in,
                              void* d_out, int out_size, void* d_ws, size_t ws_size,
                              hipStream_t stream)
{
    const float* x    = (const float*)d_in[0];
    const float* wgt  = (const float*)d_in[1];
    const float* bias = (const float*)d_in[2];
    float* out        = (float*)d_out;

    const size_t XP_BYTES = (size_t)32 * 66 * 66 * 64 * 2;   // 17,842,176
    const size_t WA_BYTES = (size_t)73728 * 2;               //    147,456

    if (ws_size < XP_BYTES + WA_BYTES) {
        dim3 grid(4, 8, 32);
        conv2d_f32_tiled<<<grid, 256, 0, stream>>>(x, wgt, bias, out);
        return;
    }

    unsigned short* xP = (unsigned short*)d_ws;
    unsigned short* wA = (unsigned short*)((char*)d_ws + XP_BYTES);

    prep_xp<<<dim3(66, 32), 256, 0, stream>>>(x, xP);
    prep_wA<<<dim3((73728 + 255) / 256), 256, 0, stream>>>(wgt, wA);
    conv_mfma13<<<dim3(64, 32), 256, 0, stream>>>(xP, wA, bias, out);
}

// Round 14
// 43.893 us; speedup vs baseline: 1.2188x; 1.2188x over previous
//
#include <hip/hip_runtime.h>

// Conv2D 3x3 pad=1: x (32,64,64,64) f32 NCHW, w (128,64,3,3) OIHW, bias(128), out (32,128,64,64) f32.
// Implicit GEMM (16x16x32 MFMA), counted-vmcnt pipelined (T3/T4/T5):
//   prep_xp:  NCHW f32 -> padded+granule-swizzled xP[n][66][66][64ci] bf16 (slot = g^(wp&7))
//   prep_wS2: OIHW f32 -> wS[18 half-planes][128 co][4 slots]x16B (slot = g^(co&3))
//   conv_mfma14: grid (16,32), 512 thr = 8 waves (2 cb x 4 h-row). Block tile 128co x 4h x 64w.
//     Wave tile 64co x 64sp (acc 4x4 = 64 AGPR). LDS 75.3KB -> 2 blocks/CU:
//     X 6 rows (50.7KB, staged ONCE via gload_lds) + W half-plane TRIPLE buffer 3x8KB.
//     Step s: issue gload W(s+2); 8 ds_read_b128 + 16 MFMA (setprio-wrapped);
//     s_waitcnt vmcnt(1) + raw s_barrier  -- NO vmcnt(0) drain anywhere in the loop.

typedef short short8 __attribute__((ext_vector_type(8)));
typedef float f32x4  __attribute__((ext_vector_type(4)));

static __device__ __forceinline__ unsigned short f2bf(float f) {
    unsigned int u = __float_as_uint(f);
    u = (u + 0x7FFFu + ((u >> 16) & 1u)) >> 16;   // RNE
    return (unsigned short)u;
}
static __device__ __forceinline__ unsigned int pk2(float lo, float hi) {
    return (unsigned int)f2bf(lo) | ((unsigned int)f2bf(hi) << 16);
}
static __device__ __forceinline__ void gload16(const void* g, void* l) {
    __builtin_amdgcn_global_load_lds(
        (const __attribute__((address_space(1))) void*)g,
        (__attribute__((address_space(3))) void*)l, 16, 0, 0);
}

// ---- prep_xp: x[n][ci][h][w] f32 -> xP[n][h'][w'][ci] bf16, padded (66x66), slot = g^(wp&7) ----
__global__ __launch_bounds__(256)
void prep_xp(const float* __restrict__ x, unsigned short* __restrict__ xP)
{
    const int hp = blockIdx.x, n = blockIdx.y, tid = threadIdx.x;
    unsigned short* rowBase = xP + (((size_t)n * 66 + hp) * 66) * 64;
    if (hp == 0 || hp == 65) {                    // zero border row
        uint4 z; z.x = z.y = z.z = z.w = 0u;
        for (int i = tid; i < 528; i += 256) ((uint4*)rowBase)[i] = z;
        return;
    }
    __shared__ float T[64][65];
    const int h = hp - 1;
    const size_t nbase = (size_t)n * 262144 + (size_t)h * 64;
    #pragma unroll
    for (int i = 0; i < 16; ++i) {
        int idx = tid + i * 256;                  // ci*64 + w
        int ci = idx >> 6, w = idx & 63;
        T[ci][w] = x[nbase + (size_t)ci * 4096 + w];
    }
    __syncthreads();
    if (tid < 16) {                               // zero border cols w'=0 and w'=65
        uint4 z; z.x = z.y = z.z = z.w = 0u;
        int wp = (tid >> 3) * 65;
        ((uint4*)(rowBase + wp * 64))[tid & 7] = z;
    }
    const int w = tid >> 2, cg = tid & 3;
    const int wp = w + 1;
    #pragma unroll
    for (int t = 0; t < 2; ++t) {
        const int g = cg * 2 + t;
        uint4 v;
        v.x = pk2(T[g*8+0][w], T[g*8+1][w]);
        v.y = pk2(T[g*8+2][w], T[g*8+3][w]);
        v.z = pk2(T[g*8+4][w], T[g*8+5][w]);
        v.w = pk2(T[g*8+6][w], T[g*8+7][w]);
        *(uint4*)(rowBase + wp * 64 + ((g ^ (wp & 7)) * 8)) = v;
    }
}

// ---- prep_wS2: w[co][ci][3][3] f32 -> wS granule u = (s*128+co)*4+slot, s = p*2+ch ----
// slot holds ci-granule g = slot^(co&3) of the half: ci = ch*32 + g*8 + j
__global__ __launch_bounds__(256)
void prep_wS2(const float* __restrict__ w, unsigned short* __restrict__ wS)
{
    int u = blockIdx.x * 256 + threadIdx.x;
    if (u >= 9216) return;
    int slot = u & 3, co = (u >> 2) & 127, s = u >> 9;
    int p = s >> 1, ch = s & 1;
    int g = slot ^ (co & 3);
    const float* src = w + (size_t)(co * 64 + ch * 32 + g * 8) * 9 + p;
    uint4 v;
    v.x = pk2(src[0*9], src[1*9]);
    v.y = pk2(src[2*9], src[3*9]);
    v.z = pk2(src[4*9], src[5*9]);
    v.w = pk2(src[6*9], src[7*9]);
    *(uint4*)(wS + (size_t)u * 8) = v;
}

// ---------------- main MFMA conv (counted-vmcnt pipeline) ----------------
#define XWIN  50688                  // 6 rows * 66 wp * 64 ci * 2B
#define WHALF 8192                   // 128 co * 32 ci * 2B
#define TOTAL_LDS (XWIN + 3*WHALF)   // 75264 -> 2 blocks/CU

__global__ __launch_bounds__(512, 4)
void conv_mfma14(const unsigned short* __restrict__ xP,
                 const unsigned short* __restrict__ wS,
                 const float* __restrict__ bias,
                 float* __restrict__ out)
{
    extern __shared__ __align__(16) char lds[];
    char* wb = lds + XWIN;              // 3 x WHALF buffers

    const int tid  = threadIdx.x;
    const int hq   = blockIdx.x;        // 0..15
    const int n    = blockIdx.y;        // 0..31
    const int h0   = hq * 4;
    const int wid  = tid >> 6, lane = tid & 63;
    const int cb   = wid >> 2;          // co half
    const int wrow = wid & 3;           // h row within tile
    const int l15  = lane & 15, l4 = lane >> 4;

    const unsigned short* xPn = xP + (size_t)n * (66 * 66 * 64);
    const char* wSb = (const char*)wS;

    // ---- prologue: X 6 padded rows (pre-swizzled src, linear dest) + W step 0 ----
    #pragma unroll
    for (int rr = 0; rr < 6; ++rr)
        gload16(xPn + (size_t)(h0 + rr) * 4224 + tid * 8, lds + rr * 8448 + tid * 16);
    if (lane < 16 && wid < 6)           // row tails (granules 512..527)
        gload16(xPn + (size_t)(h0 + wid) * 4224 + (512 + lane) * 8, lds + wid * 8448 + 8192);
    gload16(wSb + tid * 16, wb + tid * 16);                 // W step 0 -> buf 0
    __syncthreads();                                        // full drain (once)

    gload16(wSb + (512 + tid) * 16, wb + WHALF + tid * 16); // W step 1 -> buf 1 (in flight)

    f32x4 acc[4][4];
    #pragma unroll
    for (int mf = 0; mf < 4; ++mf)
        #pragma unroll
        for (int nf = 0; nf < 4; ++nf)
            acc[mf][nf] = (f32x4)0.0f;

    #pragma unroll
    for (int s = 0; s < 18; ++s) {
        const int p  = s >> 1;          // kernel plane
        const int ch = s & 1;           // ci half
        const int kh = p / 3, kw = p - kh * 3;

        if (s < 16)                     // issue W(s+2) into buf (s+2)%3
            gload16(wSb + ((s + 2) * 512 + tid) * 16,
                    wb + ((s + 2) % 3) * WHALF + tid * 16);

        const char* wcur = wb + (s % 3) * WHALF;
        const char* xrow = lds + (wrow + kh) * 8448;

        short8 Bf[4];
        #pragma unroll
        for (int nf = 0; nf < 4; ++nf) {
            const int wp = nf * 16 + l15 + kw;
            Bf[nf] = *(const short8*)(xrow + wp * 128 + (((ch * 4 + l4) ^ (wp & 7)) * 16));
        }
        short8 Af[4];
        #pragma unroll
        for (int mf = 0; mf < 4; ++mf) {
            const int co = cb * 64 + mf * 16 + l15;
            Af[mf] = *(const short8*)(wcur + co * 64 + ((l4 ^ (co & 3)) * 16));
        }
        __builtin_amdgcn_s_setprio(1);
        #pragma unroll
        for (int mf = 0; mf < 4; ++mf)
            #pragma unroll
            for (int nf = 0; nf < 4; ++nf)
                acc[mf][nf] = __builtin_amdgcn_mfma_f32_16x16x32_bf16(
                    Af[mf], Bf[nf], acc[mf][nf], 0, 0, 0);
        __builtin_amdgcn_s_setprio(0);

        if (s < 17) {
            // oldest outstanding = W(s+1): issued one full step ago -> near-zero wait
            if (s <= 15) asm volatile("s_waitcnt vmcnt(1)" ::: "memory");
            else         asm volatile("s_waitcnt vmcnt(0)" ::: "memory");
            __builtin_amdgcn_s_barrier();
            __builtin_amdgcn_sched_barrier(0);
        }
    }

    // ---- epilogue: bias + store (C/D: col=lane&15, row=(lane>>4)*4+reg) ----
    {
        const int h = h0 + wrow;
        #pragma unroll
        for (int mf = 0; mf < 4; ++mf) {
            const f32x4 bv4 = *(const f32x4*)(bias + cb * 64 + mf * 16 + l4 * 4);
            #pragma unroll
            for (int r = 0; r < 4; ++r) {
                const int co = cb * 64 + mf * 16 + l4 * 4 + r;
                float* orow = out + (((size_t)n * 128 + co) * 64 + h) * 64;
                #pragma unroll
                for (int nf = 0; nf < 4; ++nf)
                    orow[nf * 16 + l15] = acc[mf][nf][r] + bv4[r];
            }
        }
    }
}

// ---------------- fp32 fallback if ws too small ----------------
__global__ __launch_bounds__(256, 4)
void conv2d_f32_tiled(const float* __restrict__ x,
                      const float* __restrict__ wgt,
                      const float* __restrict__ bias,
                      float* __restrict__ out)
{
    __shared__ float Xlds[8][10][66];
    __shared__ float Wlds[32][72];
    const int tid = threadIdx.x;
    const int co0 = blockIdx.x * 32, h0 = blockIdx.y * 8, n = blockIdx.z;
    const int tco = tid >> 6, lane = tid & 63;
    float acc[8][8];
    #pragma unroll
    for (int i = 0; i < 8; ++i)
        #pragma unroll
        for (int j = 0; j < 8; ++j) acc[i][j] = 0.0f;
    for (int cc = 0; cc < 8; ++cc) {
        const int ci0 = cc * 8;
        for (int idx = tid; idx < 8 * 10 * 66; idx += 256) {
            const int ww = idx % 66, t = idx / 66, hh = t % 10, ci = t / 10;
            const int gh = h0 + hh - 1, gw = ww - 1;
            float v = 0.0f;
            if ((unsigned)gh < 64u && (unsigned)gw < 64u)
                v = x[(((size_t)n * 64 + ci0 + ci) * 64 + gh) * 64 + gw];
            Xlds[ci][hh][ww] = v;
        }
        for (int idx = tid; idx < 32 * 72; idx += 256) {
            const int r = idx % 72, co = idx / 72;
            Wlds[co][r] = wgt[(size_t)(co0 + co) * 576 + ci0 * 9 + r];
        }
        __syncthreads();
        for (int ci = 0; ci < 8; ++ci)
            #pragma unroll
            for (int kh = 0; kh < 3; ++kh)
                #pragma unroll
                for (int kw = 0; kw < 3; ++kw) {
                    float wv[8];
                    #pragma unroll
                    for (int i = 0; i < 8; ++i) wv[i] = Wlds[tco * 8 + i][ci * 9 + kh * 3 + kw];
                    #pragma unroll
                    for (int j = 0; j < 8; ++j) {
                        const float xv = Xlds[ci][j + kh][lane + kw];
                        #pragma unroll
                        for (int i = 0; i < 8; ++i) acc[i][j] = fmaf(wv[i], xv, acc[i][j]);
                    }
                }
        __syncthreads();
    }
    #pragma unroll
    for (int i = 0; i < 8; ++i) {
        const int co = co0 + tco * 8 + i;
        const float b = bias[co];
        #pragma unroll
        for (int j = 0; j < 8; ++j)
            out[(((size_t)n * 128 + co) * 64 + (h0 + j)) * 64 + lane] = acc[i][j] + b;
    }
}

extern "C" void kernel_launch(void* const* d_in, const int* in_sizes, int n_in,
                              void* d_out, int out_size, void* d_ws, size_t ws_size,
                              hipStream_t stream)
{
    const float* x    = (const float*)d_in[0];
    const float* wgt  = (const float*)d_in[1];
    const float* bias = (const float*)d_in[2];
    float* out        = (float*)d_out;

    const size_t XP_BYTES = (size_t)32 * 66 * 66 * 64 * 2;   // 17,842,176
    const size_t WS_BYTES = (size_t)9216 * 16;               //    147,456

    if (ws_size < XP_BYTES + WS_BYTES) {
        dim3 grid(4, 8, 32);
        conv2d_f32_tiled<<<grid, 256, 0, stream>>>(x, wgt, bias, out);
        return;
    }

    unsigned short* xP = (unsigned short*)d_ws;
    unsigned short* wS = (unsigned short*)((char*)d_ws + XP_BYTES);

    (void)hipFuncSetAttribute((const void*)conv_mfma14,
                              hipFuncAttributeMaxDynamicSharedMemorySize, TOTAL_LDS);

    prep_xp<<<dim3(66, 32), 256, 0, stream>>>(x, xP);
    prep_wS2<<<dim3(36), 256, 0, stream>>>(wgt, wS);
    conv_mfma14<<<dim3(16, 32), 512, TOTAL_LDS, stream>>>(xP, wS, bias, out);
}